// Round 3
// baseline (522.526 us; speedup 1.0000x reference)
//
#include <hip/hip_runtime.h>

#define EMB 768
#define NH 12
#define HD 64
#define BBATCH 8
#define LL 1024
#define BL (BBATCH * LL)  // 8192

typedef __attribute__((ext_vector_type(8))) short bf16x8;
typedef __attribute__((ext_vector_type(4))) float f32x4;

__device__ __forceinline__ unsigned int f2bfu(float f) {
  unsigned int u = __builtin_bit_cast(unsigned int, f);
  return (u + 0x7FFFu + ((u >> 16) & 1u)) >> 16;  // RNE f32->bf16
}

__device__ __forceinline__ f32x4 mfma16(bf16x8 a, bf16x8 b, f32x4 c) {
  return __builtin_amdgcn_mfma_f32_16x16x32_bf16(a, b, c, 0, 0, 0);
}

// ---------------- weight f32 -> bf16 conversion ----------------
__global__ __launch_bounds__(256) void convert_w_kernel(
    const float* __restrict__ wq, const float* __restrict__ wk,
    const float* __restrict__ wv, const float* __restrict__ wd,
    unsigned short* __restrict__ out) {
  const int n = EMB * EMB;
  int e = (blockIdx.x * 256 + threadIdx.x) * 4;
  int which = e / n;
  int off = e - which * n;
  const float* src = (which == 0) ? wq : (which == 1) ? wk : (which == 2) ? wv : wd;
  float4 v4 = *reinterpret_cast<const float4*>(src + off);
  uint2 o;
  o.x = f2bfu(v4.x) | (f2bfu(v4.y) << 16);
  o.y = f2bfu(v4.z) | (f2bfu(v4.w) << 16);
  *reinterpret_cast<uint2*>(out + e) = o;
}

// ---------------- shared GEMM core: 128x128 tile, K=768, dbuf LDS, 1 barrier/iter ----------------
// Computes (swapped-operand layout):
//   acc[i][j]: C = bn0 + wc*64 + i*16 + lgrp*4 + j2 (reg j2: 4 consecutive C per lane)
//              R = bm0 + wr*64 + j*16 + lrow
template <bool IN_F32>
__device__ __forceinline__ void gemm_core(const void* __restrict__ Xv,
                                          const unsigned short* __restrict__ W,
                                          char* smem, f32x4 (&acc)[4][4],
                                          int bm0, int bn0) {
  unsigned short* S = reinterpret_cast<unsigned short*>(smem);
  const int t = threadIdx.x;
  const int lane = t & 63;
  const int wid = t >> 6;
  const int wr = wid >> 1, wc = wid & 1;
  const int lrow = lane & 15, lgrp = lane >> 4;

  float4 aF[2][2];
  uint4 aB[2], bB[2];
  const int ar = t >> 2, as = t & 3;        // f32 staging: rows (ar, ar+64), slot as
  const int rb = t >> 1, sb = (t & 1) * 2;  // bf16 staging: row rb, slots sb, sb+1

  auto load_regs = [&](int kt) {
    const int k0 = kt * 32;
    if constexpr (IN_F32) {
      const float* X = reinterpret_cast<const float*>(Xv);
      const float* g0 = X + (size_t)(bm0 + ar) * EMB + k0 + as * 8;
      aF[0][0] = reinterpret_cast<const float4*>(g0)[0];
      aF[0][1] = reinterpret_cast<const float4*>(g0)[1];
      const float* g1 = g0 + (size_t)64 * EMB;
      aF[1][0] = reinterpret_cast<const float4*>(g1)[0];
      aF[1][1] = reinterpret_cast<const float4*>(g1)[1];
    } else {
      const unsigned short* X = reinterpret_cast<const unsigned short*>(Xv);
      const uint4* g = reinterpret_cast<const uint4*>(X + (size_t)(bm0 + rb) * EMB + k0 + sb * 8);
      aB[0] = g[0];
      aB[1] = g[1];
    }
    const uint4* gw = reinterpret_cast<const uint4*>(W + (size_t)(bn0 + rb) * EMB + k0 + sb * 8);
    bB[0] = gw[0];
    bB[1] = gw[1];
  };

  auto write_lds = [&](int buf) {
    unsigned short* Ab = S + buf * 8192;
    unsigned short* Bb = Ab + 4096;
    if constexpr (IN_F32) {
#pragma unroll
      for (int it = 0; it < 2; ++it) {
        int r = ar + it * 64;
        uint4 pk;
        pk.x = f2bfu(aF[it][0].x) | (f2bfu(aF[it][0].y) << 16);
        pk.y = f2bfu(aF[it][0].z) | (f2bfu(aF[it][0].w) << 16);
        pk.z = f2bfu(aF[it][1].x) | (f2bfu(aF[it][1].y) << 16);
        pk.w = f2bfu(aF[it][1].z) | (f2bfu(aF[it][1].w) << 16);
        *reinterpret_cast<uint4*>(Ab + r * 32 + ((as ^ (r & 3)) * 8)) = pk;
      }
    } else {
      *reinterpret_cast<uint4*>(Ab + rb * 32 + ((sb ^ (rb & 3)) * 8)) = aB[0];
      *reinterpret_cast<uint4*>(Ab + rb * 32 + (((sb + 1) ^ (rb & 3)) * 8)) = aB[1];
    }
    *reinterpret_cast<uint4*>(Bb + rb * 32 + ((sb ^ (rb & 3)) * 8)) = bB[0];
    *reinterpret_cast<uint4*>(Bb + rb * 32 + (((sb + 1) ^ (rb & 3)) * 8)) = bB[1];
  };

  auto compute = [&](int buf) {
    unsigned short* Ab = S + buf * 8192;
    unsigned short* Bb = Ab + 4096;
    bf16x8 a[4], b[4];
    const int sw = (lgrp ^ (lrow & 3)) * 8;
#pragma unroll
    for (int i = 0; i < 4; ++i) {
      a[i] = *reinterpret_cast<const bf16x8*>(Ab + (wr * 64 + i * 16 + lrow) * 32 + sw);
      b[i] = *reinterpret_cast<const bf16x8*>(Bb + (wc * 64 + i * 16 + lrow) * 32 + sw);
    }
    __builtin_amdgcn_s_setprio(1);
#pragma unroll
    for (int i = 0; i < 4; ++i)
#pragma unroll
      for (int j = 0; j < 4; ++j) acc[i][j] = mfma16(b[i], a[j], acc[i][j]);
    __builtin_amdgcn_s_setprio(0);
  };

  load_regs(0);
  write_lds(0);
  __syncthreads();
#pragma unroll 1
  for (int kt = 0; kt < 24; ++kt) {
    int cur = kt & 1;
    if (kt < 23) load_regs(kt + 1);
    compute(cur);
    if (kt < 23) write_lds(cur ^ 1);
    __syncthreads();
  }
}

// ---------------- fused QKV projections: z=0 Q(scaled), z=1 K, z=2 V(transposed) ----------------
__global__ __launch_bounds__(256, 4) void qkv_kernel(
    const float* __restrict__ qin, const float* __restrict__ kin, const float* __restrict__ vin,
    const unsigned short* __restrict__ wq, const unsigned short* __restrict__ wk,
    const unsigned short* __restrict__ wv, const float* __restrict__ bq,
    const float* __restrict__ bk, const float* __restrict__ bv,
    unsigned short* __restrict__ qh, unsigned short* __restrict__ kh,
    unsigned short* __restrict__ vT) {
  extern __shared__ char smem[];
  const int z = blockIdx.z;
  const float* X = (z == 0) ? qin : (z == 1) ? kin : vin;
  const unsigned short* W = (z == 0) ? wq : (z == 1) ? wk : wv;
  const float* bias = (z == 0) ? bq : (z == 1) ? bk : bv;
  const int bm0 = blockIdx.x * 128, bn0 = blockIdx.y * 128;

  f32x4 acc[4][4];
#pragma unroll
  for (int i = 0; i < 4; ++i)
#pragma unroll
    for (int j = 0; j < 4; ++j) acc[i][j] = (f32x4){0.f, 0.f, 0.f, 0.f};

  gemm_core<true>(X, W, smem, acc, bm0, bn0);

  const int t = threadIdx.x;
  const int lane = t & 63, wid = t >> 6;
  const int wr = wid >> 1, wc = wid & 1;
  const int lrow = lane & 15, lgrp = lane >> 4;

  if (z < 2) {
    const float out_scale = (z == 0) ? 0.036084391824351615f : 1.0f;  // 1/sqrt(768) on Q
    unsigned short* out = (z == 0) ? qh : kh;
#pragma unroll
    for (int i = 0; i < 4; ++i) {
      int c0 = bn0 + wc * 64 + i * 16 + lgrp * 4;
      float4 bv4 = *reinterpret_cast<const float4*>(bias + c0);
      int hh = c0 >> 6, dd0 = c0 & 63;
#pragma unroll
      for (int j = 0; j < 4; ++j) {
        int R = bm0 + wr * 64 + j * 16 + lrow;
        int bidx = R >> 10, l = R & 1023;
        uint2 o;
        o.x = f2bfu((acc[i][j][0] + bv4.x) * out_scale) |
              (f2bfu((acc[i][j][1] + bv4.y) * out_scale) << 16);
        o.y = f2bfu((acc[i][j][2] + bv4.z) * out_scale) |
              (f2bfu((acc[i][j][3] + bv4.w) * out_scale) << 16);
        *reinterpret_cast<uint2*>(out + (((size_t)(bidx * NH + hh)) << 16) + (l << 6) + dd0) = o;
      }
    }
  } else {
    __syncthreads();  // core done (ends with barrier) — safe to reuse smem
    unsigned short* T = reinterpret_cast<unsigned short*>(smem);  // [128][136]
#pragma unroll
    for (int i = 0; i < 4; ++i) {
      int c0 = wc * 64 + i * 16 + lgrp * 4;
      float4 bv4 = *reinterpret_cast<const float4*>(bias + bn0 + c0);
#pragma unroll
      for (int j = 0; j < 4; ++j) {
        int rl = wr * 64 + j * 16 + lrow;
        T[(c0 + 0) * 136 + rl] = (unsigned short)f2bfu(acc[i][j][0] + bv4.x);
        T[(c0 + 1) * 136 + rl] = (unsigned short)f2bfu(acc[i][j][1] + bv4.y);
        T[(c0 + 2) * 136 + rl] = (unsigned short)f2bfu(acc[i][j][2] + bv4.z);
        T[(c0 + 3) * 136 + rl] = (unsigned short)f2bfu(acc[i][j][3] + bv4.w);
      }
    }
    __syncthreads();
    int cl = t >> 1, rh = (t & 1) * 64;
    int C = bn0 + cl, hh = C >> 6, dd = C & 63;
    int Rg = bm0 + rh, bidx = Rg >> 10, l0 = Rg & 1023;
    size_t obase = ((size_t)(bidx * NH + hh) * 64 + dd) * 1024 + l0;
#pragma unroll
    for (int q8 = 0; q8 < 8; ++q8) {
      uint4 val = *reinterpret_cast<const uint4*>(T + cl * 136 + rh + q8 * 8);
      *reinterpret_cast<uint4*>(vT + obase + q8 * 8) = val;
    }
  }
}

// ---------------- dense: out = cat @ Wd^T + b (f32 out) ----------------
__global__ __launch_bounds__(256, 4) void dense_kernel(
    const unsigned short* __restrict__ X, const unsigned short* __restrict__ W,
    const float* __restrict__ bias, float* __restrict__ out) {
  extern __shared__ char smem[];
  const int bm0 = blockIdx.x * 128, bn0 = blockIdx.y * 128;
  f32x4 acc[4][4];
#pragma unroll
  for (int i = 0; i < 4; ++i)
#pragma unroll
    for (int j = 0; j < 4; ++j) acc[i][j] = (f32x4){0.f, 0.f, 0.f, 0.f};

  gemm_core<false>(X, W, smem, acc, bm0, bn0);

  const int t = threadIdx.x;
  const int lane = t & 63, wid = t >> 6;
  const int wr = wid >> 1, wc = wid & 1;
  const int lrow = lane & 15, lgrp = lane >> 4;
#pragma unroll
  for (int i = 0; i < 4; ++i) {
    int c0 = bn0 + wc * 64 + i * 16 + lgrp * 4;
    float4 bv4 = *reinterpret_cast<const float4*>(bias + c0);
#pragma unroll
    for (int j = 0; j < 4; ++j) {
      int R = bm0 + wr * 64 + j * 16 + lrow;
      f32x4 o;
      o[0] = acc[i][j][0] + bv4.x;
      o[1] = acc[i][j][1] + bv4.y;
      o[2] = acc[i][j][2] + bv4.z;
      o[3] = acc[i][j][3] + bv4.w;
      *reinterpret_cast<f32x4*>(out + (size_t)R * EMB + c0) = o;
    }
  }
}

// ---------------- attention ----------------
// grid (64 q-tiles, 96 pairs); block 256 = 4 waves; block: 16 q-rows, full k=1024.
// Swapped QK^T: acc[f][j] = S[k = k0 + f*16 + lgrp*4 + j][q = q0 + lrow]
__global__ __launch_bounds__(256, 4) void attn_kernel(
    const unsigned short* __restrict__ qh, const unsigned short* __restrict__ kh,
    const unsigned short* __restrict__ vhT, float* __restrict__ attn_w,
    unsigned short* __restrict__ concat) {
  __shared__ unsigned short Pl[16 * 1024];  // P tile bf16, rows 2KB, XOR-swizzled
  __shared__ float red[2][4][16];

  const int t = threadIdx.x;
  const int lane = t & 63, w = t >> 6;
  const int lrow = lane & 15, lgrp = lane >> 4;
  const int qt = blockIdx.x, pair = blockIdx.y;
  const int b = pair / NH, h = pair - b * NH;
  const int q0 = qt * 16;
  const unsigned short* qbase = qh + (size_t)pair * (LL * HD);
  const unsigned short* kbase = kh + (size_t)pair * (LL * HD);
  const unsigned short* vbase = vhT + (size_t)pair * (HD * LL);

  bf16x8 aq[2];
#pragma unroll
  for (int c = 0; c < 2; ++c)
    aq[c] = *reinterpret_cast<const bf16x8*>(qbase + (size_t)(q0 + lrow) * HD + c * 32 + lgrp * 8);

  f32x4 acc[16];
#pragma unroll
  for (int f = 0; f < 16; ++f) acc[f] = (f32x4){0.f, 0.f, 0.f, 0.f};

  const int k0 = w * 256;  // wave's 256 k-columns
  __builtin_amdgcn_s_setprio(1);
#pragma unroll
  for (int f = 0; f < 16; ++f) {
    const unsigned short* kr = kbase + (size_t)(k0 + f * 16 + lrow) * HD + lgrp * 8;
    bf16x8 b0 = *reinterpret_cast<const bf16x8*>(kr);
    bf16x8 b1 = *reinterpret_cast<const bf16x8*>(kr + 32);
    acc[f] = mfma16(b0, aq[0], acc[f]);  // swapped: K rows = m, Q rows = n
    acc[f] = mfma16(b1, aq[1], acc[f]);
  }
  __builtin_amdgcn_s_setprio(0);

  // early V prefetch (hides L2 latency under softmax + store phase)
  const unsigned short* vrow = vbase + (size_t)(w * 16 + lrow) * LL;
  bf16x8 vpre[8];
#pragma unroll
  for (int kk = 0; kk < 8; ++kk)
    vpre[kk] = *reinterpret_cast<const bf16x8*>(vrow + kk * 32 + lgrp * 8);

  // ---- softmax: per-lane 64 values of row q=lrow, then 2 shuffles, then cross-wave ----
  float m = acc[0][0];
#pragma unroll
  for (int f = 0; f < 16; ++f)
#pragma unroll
    for (int j = 0; j < 4; ++j) m = fmaxf(m, acc[f][j]);
  m = fmaxf(m, __shfl_xor(m, 16));
  m = fmaxf(m, __shfl_xor(m, 32));
  if (lane < 16) red[0][w][lane] = m;
  __syncthreads();
  float M = fmaxf(fmaxf(red[0][0][lrow], red[0][1][lrow]),
                  fmaxf(red[0][2][lrow], red[0][3][lrow]));
  float s = 0.f;
#pragma unroll
  for (int f = 0; f < 16; ++f)
#pragma unroll
    for (int j = 0; j < 4; ++j) {
      float p = __expf(acc[f][j] - M);
      acc[f][j] = p;
      s += p;
    }
  s += __shfl_xor(s, 16);
  s += __shfl_xor(s, 32);
  if (lane < 16) red[1][w][lane] = s;
  __syncthreads();
  float inv = 1.0f / (red[1][0][lrow] + red[1][1][lrow] + red[1][2][lrow] + red[1][3][lrow]);

  // ---- write attn_w (f32x4 NT) + P bf16 (ds_write_b64, swizzled) ----
  float* awp = attn_w + (size_t)pair * (LL * LL) + (size_t)(q0 + lrow) * LL + k0 + lgrp * 4;
  char* Plb = reinterpret_cast<char*>(Pl);
#pragma unroll
  for (int f = 0; f < 16; ++f) {
    float p0 = acc[f][0] * inv, p1 = acc[f][1] * inv;
    float p2 = acc[f][2] * inv, p3 = acc[f][3] * inv;
    f32x4 o = {p0, p1, p2, p3};
    __builtin_nontemporal_store(o, reinterpret_cast<f32x4*>(awp + f * 16));
    uint2 pb;
    pb.x = f2bfu(p0) | (f2bfu(p1) << 16);
    pb.y = f2bfu(p2) | (f2bfu(p3) << 16);
    int byte = (lrow * 2048 + (k0 + f * 16 + lgrp * 4) * 2) ^ ((lrow & 7) << 4);
    *reinterpret_cast<uint2*>(Plb + byte) = pb;
  }
  __syncthreads();

  // ---- PV: O[16q x 16d per wave] = P[16 x 1024] * vh[1024 x 64] ----
  f32x4 o = (f32x4){0.f, 0.f, 0.f, 0.f};
  __builtin_amdgcn_s_setprio(1);
#pragma unroll
  for (int kk = 0; kk < 32; ++kk) {
    int byte = (lrow * 2048 + (kk * 32 + lgrp * 8) * 2) ^ ((lrow & 7) << 4);
    bf16x8 pa = *reinterpret_cast<const bf16x8*>(Plb + byte);
    bf16x8 vb = (kk < 8) ? vpre[kk]
                         : *reinterpret_cast<const bf16x8*>(vrow + kk * 32 + lgrp * 8);
    o = mfma16(pa, vb, o);
  }
  __builtin_amdgcn_s_setprio(0);
#pragma unroll
  for (int j = 0; j < 4; ++j) {
    int row = q0 + lgrp * 4 + j;
    int cc = h * 64 + w * 16 + lrow;
    concat[((size_t)b * LL + row) * EMB + cc] = (unsigned short)f2bfu(o[j]);
  }
}

extern "C" void kernel_launch(void* const* d_in, const int* in_sizes, int n_in,
                              void* d_out, int out_size, void* d_ws, size_t ws_size,
                              hipStream_t stream) {
  const float* v = (const float*)d_in[0];
  const float* k = (const float*)d_in[1];
  const float* q = (const float*)d_in[2];
  const float* wq_w = (const float*)d_in[3];
  const float* wq_b = (const float*)d_in[4];
  const float* wk_w = (const float*)d_in[5];
  const float* wk_b = (const float*)d_in[6];
  const float* wv_w = (const float*)d_in[7];
  const float* wv_b = (const float*)d_in[8];
  const float* dw = (const float*)d_in[9];
  const float* db = (const float*)d_in[10];

  float* out_attn = (float*)d_out;             // [8,1024,768]
  float* out_w = out_attn + (size_t)BL * EMB;  // [8,12,1024,1024]

  if (ws_size < 55050240u) return;
  unsigned short* ws = (unsigned short*)d_ws;
  unsigned short* wqb16 = ws;
  unsigned short* wkb16 = wqb16 + EMB * EMB;
  unsigned short* wvb16 = wkb16 + EMB * EMB;
  unsigned short* wdb16 = wvb16 + EMB * EMB;
  unsigned short* qhb = wdb16 + EMB * EMB;
  unsigned short* khb = qhb + (size_t)BL * EMB;
  unsigned short* vtb = khb + (size_t)BL * EMB;
  unsigned short* cat = vtb + (size_t)BL * EMB;

  convert_w_kernel<<<dim3(2304), dim3(256), 0, stream>>>(wq_w, wk_w, wv_w, dw, ws);

  qkv_kernel<<<dim3(64, 6, 3), dim3(256), 34816, stream>>>(
      q, k, v, wqb16, wkb16, wvb16, wq_b, wk_b, wv_b, qhb, khb, vtb);

  attn_kernel<<<dim3(64, 96), dim3(256), 0, stream>>>(qhb, khb, vtb, out_w, cat);

  dense_kernel<<<dim3(64, 6), dim3(256), 32768, stream>>>(cat, wdb16, db, out_attn);
}

// Round 4
// 396.508 us; speedup vs baseline: 1.3178x; 1.3178x over previous
//
#include <hip/hip_runtime.h>

#define EMB 768
#define NH 12
#define HD 64
#define BBATCH 8
#define LL 1024
#define BL (BBATCH * LL)  // 8192

typedef __attribute__((ext_vector_type(8))) short bf16x8;
typedef __attribute__((ext_vector_type(4))) float f32x4;

__device__ __forceinline__ unsigned int f2bfu(float f) {
  unsigned int u = __builtin_bit_cast(unsigned int, f);
  return (u + 0x7FFFu + ((u >> 16) & 1u)) >> 16;  // RNE f32->bf16
}

__device__ __forceinline__ f32x4 mfma16(bf16x8 a, bf16x8 b, f32x4 c) {
  return __builtin_amdgcn_mfma_f32_16x16x32_bf16(a, b, c, 0, 0, 0);
}

// ---------------- weight f32 -> bf16 conversion ----------------
__global__ __launch_bounds__(256) void convert_w_kernel(
    const float* __restrict__ wq, const float* __restrict__ wk,
    const float* __restrict__ wv, const float* __restrict__ wd,
    unsigned short* __restrict__ out) {
  const int n = EMB * EMB;
  int e = (blockIdx.x * 256 + threadIdx.x) * 4;
  int which = e / n;
  int off = e - which * n;
  const float* src = (which == 0) ? wq : (which == 1) ? wk : (which == 2) ? wv : wd;
  float4 v4 = *reinterpret_cast<const float4*>(src + off);
  uint2 o;
  o.x = f2bfu(v4.x) | (f2bfu(v4.y) << 16);
  o.y = f2bfu(v4.z) | (f2bfu(v4.w) << 16);
  *reinterpret_cast<uint2*>(out + e) = o;
}

// ---------------- shared GEMM core: 128x128 tile, K=768, dbuf LDS, 1 barrier/iter ----------------
// Computes (swapped-operand layout):
//   acc[i][j]: C = bn0 + wc*64 + i*16 + lgrp*4 + j2 (reg j2: 4 consecutive C per lane)
//              R = bm0 + wr*64 + j*16 + lrow
template <bool IN_F32>
__device__ __forceinline__ void gemm_core(const void* __restrict__ Xv,
                                          const unsigned short* __restrict__ W,
                                          char* smem, f32x4 (&acc)[4][4],
                                          int bm0, int bn0) {
  unsigned short* S = reinterpret_cast<unsigned short*>(smem);
  const int t = threadIdx.x;
  const int lane = t & 63;
  const int wid = t >> 6;
  const int wr = wid >> 1, wc = wid & 1;
  const int lrow = lane & 15, lgrp = lane >> 4;

  float4 aF[2][2];
  uint4 aB[2], bB[2];
  const int ar = t >> 2, as = t & 3;        // f32 staging: rows (ar, ar+64), slot as
  const int rb = t >> 1, sb = (t & 1) * 2;  // bf16 staging: row rb, slots sb, sb+1

  auto load_regs = [&](int kt) {
    const int k0 = kt * 32;
    if constexpr (IN_F32) {
      const float* X = reinterpret_cast<const float*>(Xv);
      const float* g0 = X + (size_t)(bm0 + ar) * EMB + k0 + as * 8;
      aF[0][0] = reinterpret_cast<const float4*>(g0)[0];
      aF[0][1] = reinterpret_cast<const float4*>(g0)[1];
      const float* g1 = g0 + (size_t)64 * EMB;
      aF[1][0] = reinterpret_cast<const float4*>(g1)[0];
      aF[1][1] = reinterpret_cast<const float4*>(g1)[1];
    } else {
      const unsigned short* X = reinterpret_cast<const unsigned short*>(Xv);
      const uint4* g = reinterpret_cast<const uint4*>(X + (size_t)(bm0 + rb) * EMB + k0 + sb * 8);
      aB[0] = g[0];
      aB[1] = g[1];
    }
    const uint4* gw = reinterpret_cast<const uint4*>(W + (size_t)(bn0 + rb) * EMB + k0 + sb * 8);
    bB[0] = gw[0];
    bB[1] = gw[1];
  };

  auto write_lds = [&](int buf) {
    unsigned short* Ab = S + buf * 8192;
    unsigned short* Bb = Ab + 4096;
    if constexpr (IN_F32) {
#pragma unroll
      for (int it = 0; it < 2; ++it) {
        int r = ar + it * 64;
        uint4 pk;
        pk.x = f2bfu(aF[it][0].x) | (f2bfu(aF[it][0].y) << 16);
        pk.y = f2bfu(aF[it][0].z) | (f2bfu(aF[it][0].w) << 16);
        pk.z = f2bfu(aF[it][1].x) | (f2bfu(aF[it][1].y) << 16);
        pk.w = f2bfu(aF[it][1].z) | (f2bfu(aF[it][1].w) << 16);
        *reinterpret_cast<uint4*>(Ab + r * 32 + ((as ^ (r & 3)) * 8)) = pk;
      }
    } else {
      *reinterpret_cast<uint4*>(Ab + rb * 32 + ((sb ^ (rb & 3)) * 8)) = aB[0];
      *reinterpret_cast<uint4*>(Ab + rb * 32 + (((sb + 1) ^ (rb & 3)) * 8)) = aB[1];
    }
    *reinterpret_cast<uint4*>(Bb + rb * 32 + ((sb ^ (rb & 3)) * 8)) = bB[0];
    *reinterpret_cast<uint4*>(Bb + rb * 32 + (((sb + 1) ^ (rb & 3)) * 8)) = bB[1];
  };

  auto compute = [&](int buf) {
    unsigned short* Ab = S + buf * 8192;
    unsigned short* Bb = Ab + 4096;
    bf16x8 a[4], b[4];
    const int sw = (lgrp ^ (lrow & 3)) * 8;
#pragma unroll
    for (int i = 0; i < 4; ++i) {
      a[i] = *reinterpret_cast<const bf16x8*>(Ab + (wr * 64 + i * 16 + lrow) * 32 + sw);
      b[i] = *reinterpret_cast<const bf16x8*>(Bb + (wc * 64 + i * 16 + lrow) * 32 + sw);
    }
#pragma unroll
    for (int i = 0; i < 4; ++i)
#pragma unroll
      for (int j = 0; j < 4; ++j) acc[i][j] = mfma16(b[i], a[j], acc[i][j]);
  };

  load_regs(0);
  write_lds(0);
  __syncthreads();
#pragma unroll 1
  for (int kt = 0; kt < 24; ++kt) {
    int cur = kt & 1;
    if (kt < 23) load_regs(kt + 1);
    compute(cur);
    if (kt < 23) write_lds(cur ^ 1);
    __syncthreads();
  }
}

// ---------------- fused QKV projections: z=0 Q(scaled), z=1 K, z=2 V(transposed) ----------------
__global__ __launch_bounds__(256) void qkv_kernel(
    const float* __restrict__ qin, const float* __restrict__ kin, const float* __restrict__ vin,
    const unsigned short* __restrict__ wq, const unsigned short* __restrict__ wk,
    const unsigned short* __restrict__ wv, const float* __restrict__ bq,
    const float* __restrict__ bk, const float* __restrict__ bv,
    unsigned short* __restrict__ qh, unsigned short* __restrict__ kh,
    unsigned short* __restrict__ vT) {
  extern __shared__ char smem[];
  const int z = blockIdx.z;
  const float* X = (z == 0) ? qin : (z == 1) ? kin : vin;
  const unsigned short* W = (z == 0) ? wq : (z == 1) ? wk : wv;
  const float* bias = (z == 0) ? bq : (z == 1) ? bk : bv;
  const int bm0 = blockIdx.x * 128, bn0 = blockIdx.y * 128;

  f32x4 acc[4][4];
#pragma unroll
  for (int i = 0; i < 4; ++i)
#pragma unroll
    for (int j = 0; j < 4; ++j) acc[i][j] = (f32x4){0.f, 0.f, 0.f, 0.f};

  gemm_core<true>(X, W, smem, acc, bm0, bn0);

  const int t = threadIdx.x;
  const int lane = t & 63, wid = t >> 6;
  const int wr = wid >> 1, wc = wid & 1;
  const int lrow = lane & 15, lgrp = lane >> 4;

  if (z < 2) {
    const float out_scale = (z == 0) ? 0.036084391824351615f : 1.0f;  // 1/sqrt(768) on Q
    unsigned short* out = (z == 0) ? qh : kh;
#pragma unroll
    for (int i = 0; i < 4; ++i) {
      int c0 = bn0 + wc * 64 + i * 16 + lgrp * 4;
      float4 bv4 = *reinterpret_cast<const float4*>(bias + c0);
      int hh = c0 >> 6, dd0 = c0 & 63;
#pragma unroll
      for (int j = 0; j < 4; ++j) {
        int R = bm0 + wr * 64 + j * 16 + lrow;
        int bidx = R >> 10, l = R & 1023;
        uint2 o;
        o.x = f2bfu((acc[i][j][0] + bv4.x) * out_scale) |
              (f2bfu((acc[i][j][1] + bv4.y) * out_scale) << 16);
        o.y = f2bfu((acc[i][j][2] + bv4.z) * out_scale) |
              (f2bfu((acc[i][j][3] + bv4.w) * out_scale) << 16);
        *reinterpret_cast<uint2*>(out + (((size_t)(bidx * NH + hh)) << 16) + (l << 6) + dd0) = o;
      }
    }
  } else {
    __syncthreads();  // core done (ends with barrier) — safe to reuse smem
    unsigned short* T = reinterpret_cast<unsigned short*>(smem);  // [128][136]
#pragma unroll
    for (int i = 0; i < 4; ++i) {
      int c0 = wc * 64 + i * 16 + lgrp * 4;
      float4 bv4 = *reinterpret_cast<const float4*>(bias + bn0 + c0);
#pragma unroll
      for (int j = 0; j < 4; ++j) {
        int rl = wr * 64 + j * 16 + lrow;
        T[(c0 + 0) * 136 + rl] = (unsigned short)f2bfu(acc[i][j][0] + bv4.x);
        T[(c0 + 1) * 136 + rl] = (unsigned short)f2bfu(acc[i][j][1] + bv4.y);
        T[(c0 + 2) * 136 + rl] = (unsigned short)f2bfu(acc[i][j][2] + bv4.z);
        T[(c0 + 3) * 136 + rl] = (unsigned short)f2bfu(acc[i][j][3] + bv4.w);
      }
    }
    __syncthreads();
    int cl = t >> 1, rh = (t & 1) * 64;
    int C = bn0 + cl, hh = C >> 6, dd = C & 63;
    int Rg = bm0 + rh, bidx = Rg >> 10, l0 = Rg & 1023;
    size_t obase = ((size_t)(bidx * NH + hh) * 64 + dd) * 1024 + l0;
#pragma unroll
    for (int q8 = 0; q8 < 8; ++q8) {
      uint4 val = *reinterpret_cast<const uint4*>(T + cl * 136 + rh + q8 * 8);
      *reinterpret_cast<uint4*>(vT + obase + q8 * 8) = val;
    }
  }
}

// ---------------- dense: out = cat @ Wd^T + b (f32 out) ----------------
__global__ __launch_bounds__(256) void dense_kernel(
    const unsigned short* __restrict__ X, const unsigned short* __restrict__ W,
    const float* __restrict__ bias, float* __restrict__ out) {
  extern __shared__ char smem[];
  const int bm0 = blockIdx.x * 128, bn0 = blockIdx.y * 128;
  f32x4 acc[4][4];
#pragma unroll
  for (int i = 0; i < 4; ++i)
#pragma unroll
    for (int j = 0; j < 4; ++j) acc[i][j] = (f32x4){0.f, 0.f, 0.f, 0.f};

  gemm_core<false>(X, W, smem, acc, bm0, bn0);

  const int t = threadIdx.x;
  const int lane = t & 63, wid = t >> 6;
  const int wr = wid >> 1, wc = wid & 1;
  const int lrow = lane & 15, lgrp = lane >> 4;
#pragma unroll
  for (int i = 0; i < 4; ++i) {
    int c0 = bn0 + wc * 64 + i * 16 + lgrp * 4;
    float4 bv4 = *reinterpret_cast<const float4*>(bias + c0);
#pragma unroll
    for (int j = 0; j < 4; ++j) {
      int R = bm0 + wr * 64 + j * 16 + lrow;
      f32x4 o;
      o[0] = acc[i][j][0] + bv4.x;
      o[1] = acc[i][j][1] + bv4.y;
      o[2] = acc[i][j][2] + bv4.z;
      o[3] = acc[i][j][3] + bv4.w;
      *reinterpret_cast<f32x4*>(out + (size_t)R * EMB + c0) = o;
    }
  }
}

// ---------------- attention ----------------
// grid (64 q-tiles, 96 pairs); block 256 = 4 waves; block: 16 q-rows, full k=1024.
// Swapped QK^T: acc[f][j] = S[k = k0 + f*16 + lgrp*4 + j][q = q0 + lrow]
__global__ __launch_bounds__(256) void attn_kernel(
    const unsigned short* __restrict__ qh, const unsigned short* __restrict__ kh,
    const unsigned short* __restrict__ vhT, float* __restrict__ attn_w,
    unsigned short* __restrict__ concat) {
  __shared__ unsigned short Pl[16 * 1024];  // P tile bf16, rows 2KB, XOR-swizzled
  __shared__ float red[2][4][16];

  const int t = threadIdx.x;
  const int lane = t & 63, w = t >> 6;
  const int lrow = lane & 15, lgrp = lane >> 4;
  const int qt = blockIdx.x, pair = blockIdx.y;
  const int b = pair / NH, h = pair - b * NH;
  const int q0 = qt * 16;
  const unsigned short* qbase = qh + (size_t)pair * (LL * HD);
  const unsigned short* kbase = kh + (size_t)pair * (LL * HD);
  const unsigned short* vbase = vhT + (size_t)pair * (HD * LL);

  bf16x8 aq[2];
#pragma unroll
  for (int c = 0; c < 2; ++c)
    aq[c] = *reinterpret_cast<const bf16x8*>(qbase + (size_t)(q0 + lrow) * HD + c * 32 + lgrp * 8);

  f32x4 acc[16];
#pragma unroll
  for (int f = 0; f < 16; ++f) acc[f] = (f32x4){0.f, 0.f, 0.f, 0.f};

  const int k0 = w * 256;  // wave's 256 k-columns
  __builtin_amdgcn_s_setprio(1);
#pragma unroll
  for (int f = 0; f < 16; ++f) {
    const unsigned short* kr = kbase + (size_t)(k0 + f * 16 + lrow) * HD + lgrp * 8;
    bf16x8 b0 = *reinterpret_cast<const bf16x8*>(kr);
    bf16x8 b1 = *reinterpret_cast<const bf16x8*>(kr + 32);
    acc[f] = mfma16(b0, aq[0], acc[f]);  // swapped: K rows = m, Q rows = n
    acc[f] = mfma16(b1, aq[1], acc[f]);
  }
  __builtin_amdgcn_s_setprio(0);

  // early V prefetch (hides L2 latency under softmax + store phase)
  const unsigned short* vrow = vbase + (size_t)(w * 16 + lrow) * LL;
  bf16x8 vpre[8];
#pragma unroll
  for (int kk = 0; kk < 8; ++kk)
    vpre[kk] = *reinterpret_cast<const bf16x8*>(vrow + kk * 32 + lgrp * 8);

  // ---- softmax: per-lane 64 values of row q=lrow, then 2 shuffles, then cross-wave ----
  float m = acc[0][0];
#pragma unroll
  for (int f = 0; f < 16; ++f)
#pragma unroll
    for (int j = 0; j < 4; ++j) m = fmaxf(m, acc[f][j]);
  m = fmaxf(m, __shfl_xor(m, 16));
  m = fmaxf(m, __shfl_xor(m, 32));
  if (lane < 16) red[0][w][lane] = m;
  __syncthreads();
  float M = fmaxf(fmaxf(red[0][0][lrow], red[0][1][lrow]),
                  fmaxf(red[0][2][lrow], red[0][3][lrow]));
  float s = 0.f;
#pragma unroll
  for (int f = 0; f < 16; ++f)
#pragma unroll
    for (int j = 0; j < 4; ++j) {
      float p = __expf(acc[f][j] - M);
      acc[f][j] = p;
      s += p;
    }
  s += __shfl_xor(s, 16);
  s += __shfl_xor(s, 32);
  if (lane < 16) red[1][w][lane] = s;
  __syncthreads();
  float inv = 1.0f / (red[1][0][lrow] + red[1][1][lrow] + red[1][2][lrow] + red[1][3][lrow]);

  // ---- write attn_w (f32x4 NT) + P bf16 (ds_write_b64, swizzled) ----
  float* awp = attn_w + (size_t)pair * (LL * LL) + (size_t)(q0 + lrow) * LL + k0 + lgrp * 4;
  char* Plb = reinterpret_cast<char*>(Pl);
#pragma unroll
  for (int f = 0; f < 16; ++f) {
    float p0 = acc[f][0] * inv, p1 = acc[f][1] * inv;
    float p2 = acc[f][2] * inv, p3 = acc[f][3] * inv;
    f32x4 o = {p0, p1, p2, p3};
    __builtin_nontemporal_store(o, reinterpret_cast<f32x4*>(awp + f * 16));
    uint2 pb;
    pb.x = f2bfu(p0) | (f2bfu(p1) << 16);
    pb.y = f2bfu(p2) | (f2bfu(p3) << 16);
    int byte = (lrow * 2048 + (k0 + f * 16 + lgrp * 4) * 2) ^ ((lrow & 7) << 4);
    *reinterpret_cast<uint2*>(Plb + byte) = pb;
  }
  __syncthreads();

  // ---- PV: O[16q x 16d per wave] = P[16 x 1024] * vh[1024 x 64] ----
  f32x4 o = (f32x4){0.f, 0.f, 0.f, 0.f};
  __builtin_amdgcn_s_setprio(1);
#pragma unroll
  for (int kk = 0; kk < 32; ++kk) {
    int byte = (lrow * 2048 + (kk * 32 + lgrp * 8) * 2) ^ ((lrow & 7) << 4);
    bf16x8 pa = *reinterpret_cast<const bf16x8*>(Plb + byte);
    bf16x8 vb = (kk < 8) ? vpre[kk]
                         : *reinterpret_cast<const bf16x8*>(vrow + kk * 32 + lgrp * 8);
    o = mfma16(pa, vb, o);
  }
  __builtin_amdgcn_s_setprio(0);
#pragma unroll
  for (int j = 0; j < 4; ++j) {
    int row = q0 + lgrp * 4 + j;
    int cc = h * 64 + w * 16 + lrow;
    concat[((size_t)b * LL + row) * EMB + cc] = (unsigned short)f2bfu(o[j]);
  }
}

extern "C" void kernel_launch(void* const* d_in, const int* in_sizes, int n_in,
                              void* d_out, int out_size, void* d_ws, size_t ws_size,
                              hipStream_t stream) {
  const float* v = (const float*)d_in[0];
  const float* k = (const float*)d_in[1];
  const float* q = (const float*)d_in[2];
  const float* wq_w = (const float*)d_in[3];
  const float* wq_b = (const float*)d_in[4];
  const float* wk_w = (const float*)d_in[5];
  const float* wk_b = (const float*)d_in[6];
  const float* wv_w = (const float*)d_in[7];
  const float* wv_b = (const float*)d_in[8];
  const float* dw = (const float*)d_in[9];
  const float* db = (const float*)d_in[10];

  float* out_attn = (float*)d_out;             // [8,1024,768]
  float* out_w = out_attn + (size_t)BL * EMB;  // [8,12,1024,1024]

  if (ws_size < 55050240u) return;
  unsigned short* ws = (unsigned short*)d_ws;
  unsigned short* wqb16 = ws;
  unsigned short* wkb16 = wqb16 + EMB * EMB;
  unsigned short* wvb16 = wkb16 + EMB * EMB;
  unsigned short* wdb16 = wvb16 + EMB * EMB;
  unsigned short* qhb = wdb16 + EMB * EMB;
  unsigned short* khb = qhb + (size_t)BL * EMB;
  unsigned short* vtb = khb + (size_t)BL * EMB;
  unsigned short* cat = vtb + (size_t)BL * EMB;

  convert_w_kernel<<<dim3(2304), dim3(256), 0, stream>>>(wq_w, wk_w, wv_w, dw, ws);

  qkv_kernel<<<dim3(64, 6, 3), dim3(256), 34816, stream>>>(
      q, k, v, wqb16, wkb16, wvb16, wq_b, wk_b, wv_b, qhb, khb, vtb);

  attn_kernel<<<dim3(64, 96), dim3(256), 0, stream>>>(qhb, khb, vtb, out_w, cat);

  dense_kernel<<<dim3(64, 6), dim3(256), 32768, stream>>>(cat, wdb16, db, out_attn);
}